// Round 3
// baseline (299.533 us; speedup 1.0000x reference)
//
#include <hip/hip_runtime.h>
#include <hip/hip_bf16.h>
#include <stdint.h>

// B=4, T=4096, K=256, D=1024, H=16, hd=64
#define D_DIM 1024

using f32x4  = __attribute__((ext_vector_type(4))) float;
using short8 = __attribute__((ext_vector_type(8))) short;

__device__ __forceinline__ float bf2f(unsigned short u) {
    union { unsigned int i; float f; } v; v.i = ((unsigned int)u) << 16; return v.f;
}
__device__ __forceinline__ unsigned short f2bf(float f) {
    union { float f; unsigned int i; } v; v.f = f;
    unsigned int x = v.i;
    return (unsigned short)((x + 0x7fffu + ((x >> 16) & 1u)) >> 16);  // RNE
}
__device__ __forceinline__ void gload16(const void* g, void* l) {
    __builtin_amdgcn_global_load_lds(
        (const __attribute__((address_space(1))) void*)g,
        (__attribute__((address_space(3))) void*)l, 16, 0, 0);
}

// ---------------------------------------------------------------------------
// Weight fold+split: W' = gamma ⊙ W, split f32 -> hi+lo bf16.
// sel 0..2 (Wq,Wk,Wv): hi at ws+sel*4MB, lo at +2MB.  sel 3 (Wo): bf16 @12MB.
// ---------------------------------------------------------------------------
__global__ __launch_bounds__(256)
void convw_kernel(const float* __restrict__ Wq, const float* __restrict__ Wk,
                  const float* __restrict__ Wv, const float* __restrict__ Wo,
                  const float* __restrict__ gq, const float* __restrict__ gkv,
                  char* __restrict__ ws)
{
    const int e   = (blockIdx.x * 256 + threadIdx.x) * 4;
    const int sel = e >> 20;
    const int off = e & 0xFFFFF;
    const float* src = sel == 0 ? Wq : sel == 1 ? Wk : sel == 2 ? Wv : Wo;
    float4 v = *(const float4*)(src + off);
    if (sel < 3) {
        const float* gam = (sel == 0) ? gq : gkv;
        float4 g = *(const float4*)(gam + (off & 1023));
        v.x *= g.x; v.y *= g.y; v.z *= g.z; v.w *= g.w;
        ushort4 h, l;
        h.x = f2bf(v.x); l.x = f2bf(v.x - bf2f(h.x));
        h.y = f2bf(v.y); l.y = f2bf(v.y - bf2f(h.y));
        h.z = f2bf(v.z); l.z = f2bf(v.z - bf2f(h.z));
        h.w = f2bf(v.w); l.w = f2bf(v.w - bf2f(h.w));
        unsigned short* hi = (unsigned short*)(ws + (size_t)sel * (4u << 20));
        unsigned short* lo = (unsigned short*)(ws + (size_t)sel * (4u << 20) + (2u << 20));
        *(ushort4*)(hi + off) = h;
        *(ushort4*)(lo + off) = l;
    } else {
        ushort4 o;
        o.x = f2bf(v.x); o.y = f2bf(v.y); o.z = f2bf(v.z); o.w = f2bf(v.w);
        *(ushort4*)((unsigned short*)(ws + (12u << 20)) + off) = o;
    }
}

// ---------------------------------------------------------------------------
// Row rsqrt scales
// ---------------------------------------------------------------------------
__global__ __launch_bounds__(256)
void scales_kernel(const float* __restrict__ x, float* __restrict__ scale)
{
    const long row = blockIdx.x;
    float4 v = ((const float4*)(x + row * D_DIM))[threadIdx.x];
    float ss = v.x*v.x + v.y*v.y + v.z*v.z + v.w*v.w;
#pragma unroll
    for (int m = 32; m; m >>= 1) ss += __shfl_xor(ss, m);
    __shared__ float red[4];
    if ((threadIdx.x & 63) == 0) red[threadIdx.x >> 6] = ss;
    __syncthreads();
    if (threadIdx.x == 0) {
        float tot = red[0] + red[1] + red[2] + red[3];
        scale[row] = rsqrtf(tot * (1.0f / 1024.0f) + 1.1920929e-07f);
    }
}

// ---------------------------------------------------------------------------
// Split-bf16 GEMM (kv only, M=1024): O = rowscale[m]*sum_k A_f32*(Bhi+Blo)
// ---------------------------------------------------------------------------
__global__ __launch_bounds__(256)
void gemm_split(const float* __restrict__ A,
                const unsigned short* __restrict__ Bh0, const unsigned short* __restrict__ Bl0,
                const unsigned short* __restrict__ Bh1, const unsigned short* __restrict__ Bl1,
                const float* __restrict__ rowscale,
                float* __restrict__ O0, float* __restrict__ O1)
{
    __shared__ unsigned short Ah[4096], Al[4096], Bh[4096], Bl[4096];
    const unsigned short* Bhp = blockIdx.z ? Bh1 : Bh0;
    const unsigned short* Blp = blockIdx.z ? Bl1 : Bl0;
    float* O = blockIdx.z ? O1 : O0;

    const int tid = threadIdx.x, lane = tid & 63, wave = tid >> 6;
    const int wm = wave >> 1, wn = wave & 1;
    const long Arow0 = (long)blockIdx.y * 128;
    const int  Brow0 = blockIdx.x * 128;

    f32x4 acc[4][4] = {};
    const int s0 = tid, s1 = tid + 256;
    const int b0row = s0 >> 2, b0k = (s0 & 3) * 8;
    const int b1row = s1 >> 2, b1k = (s1 & 3) * 8;
    const int fr = lane & 15, ks = lane >> 4;

    for (int kt = 0; kt < 32; ++kt) {
        const int k0 = kt * 32;
        gload16(Bhp + (long)(Brow0 + b0row) * D_DIM + k0 + b0k, (char*)Bh + wave * 1024);
        gload16(Bhp + (long)(Brow0 + b1row) * D_DIM + k0 + b1k, (char*)Bh + 4096 + wave * 1024);
        gload16(Blp + (long)(Brow0 + b0row) * D_DIM + k0 + b0k, (char*)Bl + wave * 1024);
        gload16(Blp + (long)(Brow0 + b1row) * D_DIM + k0 + b1k, (char*)Bl + 4096 + wave * 1024);
#pragma unroll
        for (int j = 0; j < 4; ++j) {
            const int f = tid + j * 256;
            const int row = f >> 3, kc = f & 7;
            float4 v = *(const float4*)(A + (Arow0 + row) * D_DIM + k0 + kc * 4);
            ushort4 h, l;
            h.x = f2bf(v.x); l.x = f2bf(v.x - bf2f(h.x));
            h.y = f2bf(v.y); l.y = f2bf(v.y - bf2f(h.y));
            h.z = f2bf(v.z); l.z = f2bf(v.z - bf2f(h.z));
            h.w = f2bf(v.w); l.w = f2bf(v.w - bf2f(h.w));
            *(ushort4*)((char*)Ah + f * 8) = h;
            *(ushort4*)((char*)Al + f * 8) = l;
        }
        __syncthreads();

        short8 ah[4], al[4], bh[4], bl[4];
        const unsigned short* Ahq = Ah + (wm * 64 + fr) * 32 + ks * 8;
        const unsigned short* Alq = Al + (wm * 64 + fr) * 32 + ks * 8;
        const unsigned short* Bhq = Bh + (wn * 64 + fr) * 32 + ks * 8;
        const unsigned short* Blq = Bl + (wn * 64 + fr) * 32 + ks * 8;
#pragma unroll
        for (int mi = 0; mi < 4; ++mi) {
            ah[mi] = *(const short8*)(Ahq + mi * 512);
            al[mi] = *(const short8*)(Alq + mi * 512);
        }
#pragma unroll
        for (int ni = 0; ni < 4; ++ni) {
            bh[ni] = *(const short8*)(Bhq + ni * 512);
            bl[ni] = *(const short8*)(Blq + ni * 512);
        }
#pragma unroll
        for (int mi = 0; mi < 4; ++mi)
#pragma unroll
            for (int ni = 0; ni < 4; ++ni) {
                acc[mi][ni] = __builtin_amdgcn_mfma_f32_16x16x32_bf16(ah[mi], bh[ni], acc[mi][ni], 0, 0, 0);
                acc[mi][ni] = __builtin_amdgcn_mfma_f32_16x16x32_bf16(al[mi], bh[ni], acc[mi][ni], 0, 0, 0);
                acc[mi][ni] = __builtin_amdgcn_mfma_f32_16x16x32_bf16(ah[mi], bl[ni], acc[mi][ni], 0, 0, 0);
            }
        __syncthreads();
    }

    const int c = lane & 15, r0 = (lane >> 4) * 4;
#pragma unroll
    for (int mi = 0; mi < 4; ++mi)
#pragma unroll
        for (int ni = 0; ni < 4; ++ni)
#pragma unroll
            for (int j = 0; j < 4; ++j) {
                const long row = Arow0 + wm * 64 + mi * 16 + r0 + j;
                const int  col = Brow0 + wn * 64 + ni * 16 + c;
                O[row * D_DIM + col] = acc[mi][ni][j] * rowscale[row];
            }
}

// ---------------------------------------------------------------------------
// FUSED q-projection + band attention.
// Block: 64 tokens x ALL 1024 cols, 8 waves (each 32 rows x 256 cols = 4 heads).
// q stays f32 in acc; attention fully in-register; writes ao bf16.
// LDS: A hi/lo 2x4KB + W hi/lo 2x64KB = 136KB -> 1 block/CU.
// ---------------------------------------------------------------------------
__global__ __launch_bounds__(512)
void qattn_kernel(const float* __restrict__ x,
                  const unsigned short* __restrict__ Wh,
                  const unsigned short* __restrict__ Wl,
                  const float* __restrict__ rowscale,
                  const float* __restrict__ kf, const float* __restrict__ vf,
                  const int* __restrict__ cidx,
                  unsigned short* __restrict__ ao)
{
    __shared__ unsigned short Ah[64 * 32], Al[64 * 32];      // 4KB each
    __shared__ unsigned short Bh[1024 * 32], Bl[1024 * 32];  // 64KB each

    const int tid = threadIdx.x, lane = tid & 63, wave = tid >> 6;
    const int wm = wave >> 2, wn = wave & 3;    // 2 x 4 wave grid
    const int row0 = blockIdx.x * 64;
    const int b = row0 >> 12;
    const int fr = lane & 15, ks = lane >> 4;

    f32x4 acc[2][16] = {};

    // A staging role: thread loads one float4 of x per K-step
    const int arow = tid >> 3, akc = (tid & 7) * 4;
    const float ascale = rowscale[row0 + arow];
    const float* xrow = x + (long)(row0 + arow) * D_DIM + akc;

    // prologue: issue stage for kt=0
#pragma unroll
    for (int j = 0; j < 8; ++j) {
        const int s = tid + j * 512;
        const long go = (long)(s >> 2) * D_DIM + (s & 3) * 8;
        gload16(Wh + go, (char*)Bh + s * 16);
        gload16(Wl + go, (char*)Bl + s * 16);
    }
    float4 xv = *(const float4*)(xrow);

    for (int kt = 0; kt < 32; ++kt) {
        // A split + LDS write (xv loaded long ago)
        {
            float4 v = xv;
            v.x *= ascale; v.y *= ascale; v.z *= ascale; v.w *= ascale;
            ushort4 h, l;
            h.x = f2bf(v.x); l.x = f2bf(v.x - bf2f(h.x));
            h.y = f2bf(v.y); l.y = f2bf(v.y - bf2f(h.y));
            h.z = f2bf(v.z); l.z = f2bf(v.z - bf2f(h.z));
            h.w = f2bf(v.w); l.w = f2bf(v.w - bf2f(h.w));
            *(ushort4*)((char*)Ah + tid * 8) = h;
            *(ushort4*)((char*)Al + tid * 8) = l;
        }
        __syncthreads();   // staging of tile kt complete (vmcnt+lgkm drained)

        short8 ahf[2], alf[2];
        const int abase = (wm * 32 + fr) * 32 + ks * 8;
        ahf[0] = *(const short8*)(Ah + abase);
        ahf[1] = *(const short8*)(Ah + abase + 512);
        alf[0] = *(const short8*)(Al + abase);
        alf[1] = *(const short8*)(Al + abase + 512);
        short8 bhf[16], blf[16];
#pragma unroll
        for (int ni = 0; ni < 16; ++ni) {
            const int bbase = (wn * 256 + ni * 16 + fr) * 32 + ks * 8;
            bhf[ni] = *(const short8*)(Bh + bbase);
            blf[ni] = *(const short8*)(Bl + bbase);
        }
        __syncthreads();   // all reads done; LDS free for next tile

        // issue next tile's staging NOW; MFMAs below hide its flight
        if (kt < 31) {
            const int k0n = (kt + 1) * 32;
#pragma unroll
            for (int j = 0; j < 8; ++j) {
                const int s = tid + j * 512;
                const long go = (long)(s >> 2) * D_DIM + k0n + (s & 3) * 8;
                gload16(Wh + go, (char*)Bh + s * 16);
                gload16(Wl + go, (char*)Bl + s * 16);
            }
            xv = *(const float4*)(xrow + k0n);
        }

#pragma unroll
        for (int ni = 0; ni < 16; ++ni)
#pragma unroll
            for (int mi = 0; mi < 2; ++mi) {
                acc[mi][ni] = __builtin_amdgcn_mfma_f32_16x16x32_bf16(ahf[mi], bhf[ni], acc[mi][ni], 0, 0, 0);
                acc[mi][ni] = __builtin_amdgcn_mfma_f32_16x16x32_bf16(alf[mi], bhf[ni], acc[mi][ni], 0, 0, 0);
                acc[mi][ni] = __builtin_amdgcn_mfma_f32_16x16x32_bf16(ahf[mi], blf[ni], acc[mi][ni], 0, 0, 0);
            }
    }

    // ---- in-register band attention ----
    // lane holds: col c = lane&15 within frag; rows rg*4+j. acc = q (f32, scaled).
    const int c = lane & 15, rg = lane >> 4;
#pragma unroll
    for (int hq = 0; hq < 4; ++hq) {           // head within wave
        const int headbase = (wn * 4 + hq) * 64;
        float wb[2][4][3];
        int   pp[2][4][3];
#pragma unroll
        for (int mi = 0; mi < 2; ++mi)
#pragma unroll
            for (int j = 0; j < 4; ++j) {
                const int tok = row0 + wm * 32 + mi * 16 + rg * 4 + j;
                const int idx = cidx[tok];
                float wv_[3]; int pv_[3];
                float wsum = 0.f;
#pragma unroll
                for (int dp = 0; dp < 3; ++dp) {
                    const int p = idx + dp - 1;
                    const bool valid = (p >= 0) && (p < 256);
                    const int pc = valid ? p : 0;
                    const float* kr = kf + (long)(b * 256 + pc) * D_DIM + headbase + c;
                    float dot = acc[mi][4 * hq + 0][j] * kr[0]
                              + acc[mi][4 * hq + 1][j] * kr[16]
                              + acc[mi][4 * hq + 2][j] * kr[32]
                              + acc[mi][4 * hq + 3][j] * kr[48];
                    dot += __shfl_xor(dot, 1);
                    dot += __shfl_xor(dot, 2);
                    dot += __shfl_xor(dot, 4);
                    dot += __shfl_xor(dot, 8);
                    const float s = dot * 0.125f;
                    const float w = (valid && s > 0.f) ? s * s : 0.f;
                    wsum += w; wv_[dp] = w; pv_[dp] = pc;
                }
                const float inv = 1.0f / fmaxf(wsum, 1e-6f);
#pragma unroll
                for (int dp = 0; dp < 3; ++dp) {
                    wb[mi][j][dp] = wv_[dp] * inv;
                    pp[mi][j][dp] = pv_[dp];
                }
            }
        // overwrite this head's acc frags with attention output
#pragma unroll
        for (int hh = 0; hh < 4; ++hh) {
            const int ni = 4 * hq + hh;
            const int gcol = wn * 256 + ni * 16 + c;
#pragma unroll
            for (int mi = 0; mi < 2; ++mi)
#pragma unroll
                for (int j = 0; j < 4; ++j) {
                    float a = 0.f;
#pragma unroll
                    for (int dp = 0; dp < 3; ++dp)
                        a += wb[mi][j][dp] *
                             vf[(long)(b * 256 + pp[mi][j][dp]) * D_DIM + gcol];
                    acc[mi][ni][j] = a;
                }
        }
    }

    // store ao (bf16)
#pragma unroll
    for (int mi = 0; mi < 2; ++mi)
#pragma unroll
        for (int ni = 0; ni < 16; ++ni)
#pragma unroll
            for (int j = 0; j < 4; ++j) {
                const long tok = row0 + wm * 32 + mi * 16 + rg * 4 + j;
                const int gcol = wn * 256 + ni * 16 + c;
                ao[tok * D_DIM + gcol] = f2bf(acc[mi][ni][j]);
            }
}

// ---------------------------------------------------------------------------
// Plain bf16 GEMM (m97): out = resid + ao @ Wo^T, f32 out.
// ---------------------------------------------------------------------------
__global__ __launch_bounds__(256)
void gemm_out(const unsigned short* __restrict__ A, const unsigned short* __restrict__ W,
              float* __restrict__ C, const float* __restrict__ resid)
{
    __shared__ unsigned short As[4096];
    __shared__ unsigned short Bs[4096];

    const int tid = threadIdx.x, lane = tid & 63, wave = tid >> 6;
    const int wm = wave >> 1, wn = wave & 1;
    const long Arow0 = (long)blockIdx.y * 128;
    const int  Brow0 = blockIdx.x * 128;

    f32x4 acc[4][4] = {};
    const int s0 = tid, s1 = tid + 256;
    const int a0row = s0 >> 2, a0k = (s0 & 3) * 8;
    const int a1row = s1 >> 2, a1k = (s1 & 3) * 8;
    const int fr = lane & 15, ks = lane >> 4;

    for (int kt = 0; kt < 32; ++kt) {
        const int k0 = kt * 32;
        gload16(A + (Arow0 + a0row) * D_DIM + k0 + a0k, (char*)As + wave * 1024);
        gload16(A + (Arow0 + a1row) * D_DIM + k0 + a1k, (char*)As + 4096 + wave * 1024);
        gload16(W + (long)(Brow0 + a0row) * D_DIM + k0 + a0k, (char*)Bs + wave * 1024);
        gload16(W + (long)(Brow0 + a1row) * D_DIM + k0 + a1k, (char*)Bs + 4096 + wave * 1024);
        __syncthreads();

        short8 a[4], bfr[4];
        const unsigned short* Ap = As + (wm * 64 + fr) * 32 + ks * 8;
        const unsigned short* Bp = Bs + (wn * 64 + fr) * 32 + ks * 8;
#pragma unroll
        for (int mi = 0; mi < 4; ++mi) a[mi] = *(const short8*)(Ap + mi * 512);
#pragma unroll
        for (int ni = 0; ni < 4; ++ni) bfr[ni] = *(const short8*)(Bp + ni * 512);
#pragma unroll
        for (int mi = 0; mi < 4; ++mi)
#pragma unroll
            for (int ni = 0; ni < 4; ++ni)
                acc[mi][ni] = __builtin_amdgcn_mfma_f32_16x16x32_bf16(a[mi], bfr[ni], acc[mi][ni], 0, 0, 0);
        __syncthreads();
    }

    const int c = lane & 15, r0 = (lane >> 4) * 4;
#pragma unroll
    for (int mi = 0; mi < 4; ++mi)
#pragma unroll
        for (int ni = 0; ni < 4; ++ni)
#pragma unroll
            for (int j = 0; j < 4; ++j) {
                const long row = Arow0 + wm * 64 + mi * 16 + r0 + j;
                const int  col = Brow0 + wn * 64 + ni * 16 + c;
                C[row * D_DIM + col] = resid[row * D_DIM + col] + acc[mi][ni][j];
            }
}

// ---------------------------------------------------------------------------
extern "C" void kernel_launch(void* const* d_in, const int* in_sizes, int n_in,
                              void* d_out, int out_size, void* d_ws, size_t ws_size,
                              hipStream_t stream)
{
    const float* x    = (const float*)d_in[0];
    const float* ctx  = (const float*)d_in[1];
    const int*   cidx = (const int*)d_in[2];
    const float* gq   = (const float*)d_in[3];
    const float* gkv  = (const float*)d_in[4];
    const float* Wq   = (const float*)d_in[5];
    const float* Wk   = (const float*)d_in[6];
    const float* Wv   = (const float*)d_in[7];
    const float* Wo   = (const float*)d_in[8];
    float* out = (float*)d_out;

    char* ws = (char*)d_ws;
    const size_t MB = 1 << 20;
    unsigned short* wq_hi = (unsigned short*)(ws + 0 * MB);
    unsigned short* wq_lo = (unsigned short*)(ws + 2 * MB);
    unsigned short* wk_hi = (unsigned short*)(ws + 4 * MB);
    unsigned short* wk_lo = (unsigned short*)(ws + 6 * MB);
    unsigned short* wv_hi = (unsigned short*)(ws + 8 * MB);
    unsigned short* wv_lo = (unsigned short*)(ws + 10 * MB);
    unsigned short* wo_b  = (unsigned short*)(ws + 12 * MB);
    float* scale_x = (float*)(ws + 14 * MB);            // 64KB
    float* scale_c = (float*)(ws + 14 * MB + 131072);   // 4KB
    float* k_f = (float*)(ws + 15 * MB);                // 4MB
    float* v_f = (float*)(ws + 19 * MB);                // 4MB
    unsigned short* ao_b = (unsigned short*)(ws + 23 * MB);  // 32MB; total 55MB

    // 1. fold gamma into Wq/Wk/Wv, split hi/lo; Wo -> bf16
    convw_kernel<<<4096, 256, 0, stream>>>(Wq, Wk, Wv, Wo, gq, gkv, ws);
    // 2. rmsnorm row scales
    scales_kernel<<<16384, 256, 0, stream>>>(x, scale_x);
    scales_kernel<<<1024, 256, 0, stream>>>(ctx, scale_c);
    // 3. k,v (split precision, f32 out)
    gemm_split<<<dim3(8, 8, 2), 256, 0, stream>>>(ctx, wk_hi, wk_lo, wv_hi, wv_lo,
                                                  scale_c, k_f, v_f);
    // 4. fused q projection + band attention -> ao (bf16)
    qattn_kernel<<<256, 512, 0, stream>>>(x, wq_hi, wq_lo, scale_x, k_f, v_f,
                                          cidx, ao_b);
    // 5. out = x + ao @ Wo^T
    gemm_out<<<dim3(8, 128, 1), 256, 0, stream>>>(ao_b, wo_b, out, x);
}

// Round 4
// 241.307 us; speedup vs baseline: 1.2413x; 1.2413x over previous
//
#include <hip/hip_runtime.h>
#include <hip/hip_bf16.h>
#include <stdint.h>

// B=4, T=4096, K=256, D=1024, H=16, hd=64
#define D_DIM 1024

using f32x4  = __attribute__((ext_vector_type(4))) float;
using short8 = __attribute__((ext_vector_type(8))) short;

__device__ __forceinline__ float bf2f(unsigned short u) {
    union { unsigned int i; float f; } v; v.i = ((unsigned int)u) << 16; return v.f;
}
__device__ __forceinline__ unsigned short f2bf(float f) {
    union { float f; unsigned int i; } v; v.f = f;
    unsigned int x = v.i;
    return (unsigned short)((x + 0x7fffu + ((x >> 16) & 1u)) >> 16);  // RNE
}
__device__ __forceinline__ void gload16(const void* g, void* l) {
    __builtin_amdgcn_global_load_lds(
        (const __attribute__((address_space(1))) void*)g,
        (__attribute__((address_space(3))) void*)l, 16, 0, 0);
}

// XCD-aware decode for 256-block grids: 4 col-blocks x 64 row-blocks.
// bits [2:0]=xcd -> by%8, [4:3]=bx, [7:5]=by>>3. Same-by blocks (sharing the
// A-tile) land on one XCD; all 4 B-panels stay L2-resident per XCD.
__device__ __forceinline__ void decode_grid(int lin, int& bx, int& by) {
    bx = (lin >> 3) & 3;
    by = ((lin >> 5) << 3) | (lin & 7);
}

// ---------------------------------------------------------------------------
// Weight fold+split: W' = gamma ⊙ W, split f32 -> hi+lo bf16.
// sel 0..2 (Wq,Wk,Wv): hi at ws+sel*4MB, lo at +2MB.  sel 3 (Wo): bf16 @12MB.
// ---------------------------------------------------------------------------
__global__ __launch_bounds__(256)
void convw_kernel(const float* __restrict__ Wq, const float* __restrict__ Wk,
                  const float* __restrict__ Wv, const float* __restrict__ Wo,
                  const float* __restrict__ gq, const float* __restrict__ gkv,
                  char* __restrict__ ws)
{
    const int e   = (blockIdx.x * 256 + threadIdx.x) * 4;
    const int sel = e >> 20;
    const int off = e & 0xFFFFF;
    const float* src = sel == 0 ? Wq : sel == 1 ? Wk : sel == 2 ? Wv : Wo;
    float4 v = *(const float4*)(src + off);
    if (sel < 3) {
        const float* gam = (sel == 0) ? gq : gkv;
        float4 g = *(const float4*)(gam + (off & 1023));
        v.x *= g.x; v.y *= g.y; v.z *= g.z; v.w *= g.w;
        ushort4 h, l;
        h.x = f2bf(v.x); l.x = f2bf(v.x - bf2f(h.x));
        h.y = f2bf(v.y); l.y = f2bf(v.y - bf2f(h.y));
        h.z = f2bf(v.z); l.z = f2bf(v.z - bf2f(h.z));
        h.w = f2bf(v.w); l.w = f2bf(v.w - bf2f(h.w));
        unsigned short* hi = (unsigned short*)(ws + (size_t)sel * (4u << 20));
        unsigned short* lo = (unsigned short*)(ws + (size_t)sel * (4u << 20) + (2u << 20));
        *(ushort4*)(hi + off) = h;
        *(ushort4*)(lo + off) = l;
    } else {
        ushort4 o;
        o.x = f2bf(v.x); o.y = f2bf(v.y); o.z = f2bf(v.z); o.w = f2bf(v.w);
        *(ushort4*)((unsigned short*)(ws + (12u << 20)) + off) = o;
    }
}

// ---------------------------------------------------------------------------
// Row rsqrt scales
// ---------------------------------------------------------------------------
__global__ __launch_bounds__(256)
void scales_kernel(const float* __restrict__ x, float* __restrict__ scale)
{
    const long row = blockIdx.x;
    float4 v = ((const float4*)(x + row * D_DIM))[threadIdx.x];
    float ss = v.x*v.x + v.y*v.y + v.z*v.z + v.w*v.w;
#pragma unroll
    for (int m = 32; m; m >>= 1) ss += __shfl_xor(ss, m);
    __shared__ float red[4];
    if ((threadIdx.x & 63) == 0) red[threadIdx.x >> 6] = ss;
    __syncthreads();
    if (threadIdx.x == 0) {
        float tot = red[0] + red[1] + red[2] + red[3];
        scale[row] = rsqrtf(tot * (1.0f / 1024.0f) + 1.1920929e-07f);
    }
}

// ---------------------------------------------------------------------------
// Split-bf16 GEMM (kv only, M=1024): O = rowscale[m]*sum_k A_f32*(Bhi+Blo)
// (validated round 2; unchanged)
// ---------------------------------------------------------------------------
__global__ __launch_bounds__(256)
void gemm_split(const float* __restrict__ A,
                const unsigned short* __restrict__ Bh0, const unsigned short* __restrict__ Bl0,
                const unsigned short* __restrict__ Bh1, const unsigned short* __restrict__ Bl1,
                const float* __restrict__ rowscale,
                float* __restrict__ O0, float* __restrict__ O1)
{
    __shared__ unsigned short Ah[4096], Al[4096], Bh[4096], Bl[4096];
    const unsigned short* Bhp = blockIdx.z ? Bh1 : Bh0;
    const unsigned short* Blp = blockIdx.z ? Bl1 : Bl0;
    float* O = blockIdx.z ? O1 : O0;

    const int tid = threadIdx.x, lane = tid & 63, wave = tid >> 6;
    const int wm = wave >> 1, wn = wave & 1;
    const long Arow0 = (long)blockIdx.y * 128;
    const int  Brow0 = blockIdx.x * 128;

    f32x4 acc[4][4] = {};
    const int s0 = tid, s1 = tid + 256;
    const int b0row = s0 >> 2, b0k = (s0 & 3) * 8;
    const int b1row = s1 >> 2, b1k = (s1 & 3) * 8;
    const int fr = lane & 15, ks = lane >> 4;

    for (int kt = 0; kt < 32; ++kt) {
        const int k0 = kt * 32;
        gload16(Bhp + (long)(Brow0 + b0row) * D_DIM + k0 + b0k, (char*)Bh + wave * 1024);
        gload16(Bhp + (long)(Brow0 + b1row) * D_DIM + k0 + b1k, (char*)Bh + 4096 + wave * 1024);
        gload16(Blp + (long)(Brow0 + b0row) * D_DIM + k0 + b0k, (char*)Bl + wave * 1024);
        gload16(Blp + (long)(Brow0 + b1row) * D_DIM + k0 + b1k, (char*)Bl + 4096 + wave * 1024);
#pragma unroll
        for (int j = 0; j < 4; ++j) {
            const int f = tid + j * 256;
            const int row = f >> 3, kc = f & 7;
            float4 v = *(const float4*)(A + (Arow0 + row) * D_DIM + k0 + kc * 4);
            ushort4 h, l;
            h.x = f2bf(v.x); l.x = f2bf(v.x - bf2f(h.x));
            h.y = f2bf(v.y); l.y = f2bf(v.y - bf2f(h.y));
            h.z = f2bf(v.z); l.z = f2bf(v.z - bf2f(h.z));
            h.w = f2bf(v.w); l.w = f2bf(v.w - bf2f(h.w));
            *(ushort4*)((char*)Ah + f * 8) = h;
            *(ushort4*)((char*)Al + f * 8) = l;
        }
        __syncthreads();

        short8 ah[4], al[4], bh[4], bl[4];
        const unsigned short* Ahq = Ah + (wm * 64 + fr) * 32 + ks * 8;
        const unsigned short* Alq = Al + (wm * 64 + fr) * 32 + ks * 8;
        const unsigned short* Bhq = Bh + (wn * 64 + fr) * 32 + ks * 8;
        const unsigned short* Blq = Bl + (wn * 64 + fr) * 32 + ks * 8;
#pragma unroll
        for (int mi = 0; mi < 4; ++mi) {
            ah[mi] = *(const short8*)(Ahq + mi * 512);
            al[mi] = *(const short8*)(Alq + mi * 512);
        }
#pragma unroll
        for (int ni = 0; ni < 4; ++ni) {
            bh[ni] = *(const short8*)(Bhq + ni * 512);
            bl[ni] = *(const short8*)(Blq + ni * 512);
        }
#pragma unroll
        for (int mi = 0; mi < 4; ++mi)
#pragma unroll
            for (int ni = 0; ni < 4; ++ni) {
                acc[mi][ni] = __builtin_amdgcn_mfma_f32_16x16x32_bf16(ah[mi], bh[ni], acc[mi][ni], 0, 0, 0);
                acc[mi][ni] = __builtin_amdgcn_mfma_f32_16x16x32_bf16(al[mi], bh[ni], acc[mi][ni], 0, 0, 0);
                acc[mi][ni] = __builtin_amdgcn_mfma_f32_16x16x32_bf16(ah[mi], bl[ni], acc[mi][ni], 0, 0, 0);
            }
        __syncthreads();
    }

    const int c = lane & 15, r0 = (lane >> 4) * 4;
#pragma unroll
    for (int mi = 0; mi < 4; ++mi)
#pragma unroll
        for (int ni = 0; ni < 4; ++ni)
#pragma unroll
            for (int j = 0; j < 4; ++j) {
                const long row = Arow0 + wm * 64 + mi * 16 + r0 + j;
                const int  col = Brow0 + wn * 64 + ni * 16 + c;
                O[row * D_DIM + col] = acc[mi][ni][j] * rowscale[row];
            }
}

// ---------------------------------------------------------------------------
// FUSED q-projection + band attention, BM=256 x BN=256 (4 heads/block).
// 8 waves (2x4): wave = 128 rows x 64 cols (one head). Double-buffered LDS,
// one barrier per K-step. acc[8][4], 96 MFMA vs 24 ds_read_b128 per K-step.
// LDS: (Ah,Al,Bh,Bl) x 2 x 16KB = 128KB -> 1 block/CU.
// ---------------------------------------------------------------------------
__global__ __launch_bounds__(512, 2)
void qattn2_kernel(const float* __restrict__ x,
                   const unsigned short* __restrict__ Wh,
                   const unsigned short* __restrict__ Wl,
                   const float* __restrict__ rowscale,
                   const float* __restrict__ kf, const float* __restrict__ vf,
                   const int* __restrict__ cidx,
                   unsigned short* __restrict__ ao)
{
    __shared__ unsigned short Ah[2][8192], Al[2][8192];
    __shared__ unsigned short Bh[2][8192], Bl[2][8192];

    int bx, by;
    decode_grid(blockIdx.x, bx, by);
    const int row0 = by * 256;          // token base
    const int col0 = bx * 256;          // q-col base (heads bx*4 .. +3)
    const int b = row0 >> 12;

    const int tid = threadIdx.x, lane = tid & 63, wave = tid >> 6;
    const int wm = wave >> 2, wn = wave & 3;
    const int fr = lane & 15, ks = lane >> 4;

    f32x4 acc[8][4] = {};

    // B staging: 2 x 16B segs/thread per buffer
    const int bs_row0 = tid >> 2,          bs_k0 = (tid & 3) * 8;
    const int bs_row1 = (tid >> 2) + 128;  // (tid+512)>>2
    // A staging: 4 float4 segs/thread; s=tid+i*512 -> row=(tid>>3)+i*64, kc=(tid&7)*4
    const int a_row = tid >> 3;
    const int a_kc  = (tid & 7) * 4;
    float sc[4];
#pragma unroll
    for (int i = 0; i < 4; ++i) sc[i] = rowscale[row0 + a_row + i * 64];

    float4 xv[4];
    // ---- prologue: stage tile 0 into buf 0 ----
    gload16(Wh + (long)(col0 + bs_row0) * D_DIM + bs_k0, (char*)&Bh[0][0] + tid * 16);
    gload16(Wh + (long)(col0 + bs_row1) * D_DIM + bs_k0, (char*)&Bh[0][0] + (tid + 512) * 16);
    gload16(Wl + (long)(col0 + bs_row0) * D_DIM + bs_k0, (char*)&Bl[0][0] + tid * 16);
    gload16(Wl + (long)(col0 + bs_row1) * D_DIM + bs_k0, (char*)&Bl[0][0] + (tid + 512) * 16);
#pragma unroll
    for (int i = 0; i < 4; ++i)
        xv[i] = *(const float4*)(x + (long)(row0 + a_row + i * 64) * D_DIM + a_kc);
#pragma unroll
    for (int i = 0; i < 4; ++i) {
        float4 v = xv[i];
        v.x *= sc[i]; v.y *= sc[i]; v.z *= sc[i]; v.w *= sc[i];
        ushort4 h, l;
        h.x = f2bf(v.x); l.x = f2bf(v.x - bf2f(h.x));
        h.y = f2bf(v.y); l.y = f2bf(v.y - bf2f(h.y));
        h.z = f2bf(v.z); l.z = f2bf(v.z - bf2f(h.z));
        h.w = f2bf(v.w); l.w = f2bf(v.w - bf2f(h.w));
        const int off = (a_row + i * 64) * 32 + a_kc;
        *(ushort4*)(&Ah[0][off]) = h;
        *(ushort4*)(&Al[0][off]) = l;
    }
    __syncthreads();

    int cur = 0;
    for (int t = 0; t < 32; ++t) {
        const int nxt = cur ^ 1;
        if (t < 31) {
            const int k0 = (t + 1) * 32;
            gload16(Wh + (long)(col0 + bs_row0) * D_DIM + k0 + bs_k0, (char*)&Bh[nxt][0] + tid * 16);
            gload16(Wh + (long)(col0 + bs_row1) * D_DIM + k0 + bs_k0, (char*)&Bh[nxt][0] + (tid + 512) * 16);
            gload16(Wl + (long)(col0 + bs_row0) * D_DIM + k0 + bs_k0, (char*)&Bl[nxt][0] + tid * 16);
            gload16(Wl + (long)(col0 + bs_row1) * D_DIM + k0 + bs_k0, (char*)&Bl[nxt][0] + (tid + 512) * 16);
#pragma unroll
            for (int i = 0; i < 4; ++i)
                xv[i] = *(const float4*)(x + (long)(row0 + a_row + i * 64) * D_DIM + k0 + a_kc);
        }

        // compute tile cur
        short8 bh[4], bl[4];
#pragma unroll
        for (int ni = 0; ni < 4; ++ni) {
            const int boff = (wn * 64 + ni * 16 + fr) * 32 + ks * 8;
            bh[ni] = *(const short8*)(&Bh[cur][boff]);
            bl[ni] = *(const short8*)(&Bl[cur][boff]);
        }
#pragma unroll
        for (int mi = 0; mi < 8; ++mi) {
            const int aoff = (wm * 128 + mi * 16 + fr) * 32 + ks * 8;
            const short8 ah = *(const short8*)(&Ah[cur][aoff]);
            const short8 al = *(const short8*)(&Al[cur][aoff]);
#pragma unroll
            for (int ni = 0; ni < 4; ++ni) {
                acc[mi][ni] = __builtin_amdgcn_mfma_f32_16x16x32_bf16(ah, bh[ni], acc[mi][ni], 0, 0, 0);
                acc[mi][ni] = __builtin_amdgcn_mfma_f32_16x16x32_bf16(al, bh[ni], acc[mi][ni], 0, 0, 0);
                acc[mi][ni] = __builtin_amdgcn_mfma_f32_16x16x32_bf16(ah, bl[ni], acc[mi][ni], 0, 0, 0);
            }
        }

        if (t < 31) {
#pragma unroll
            for (int i = 0; i < 4; ++i) {
                float4 v = xv[i];
                v.x *= sc[i]; v.y *= sc[i]; v.z *= sc[i]; v.w *= sc[i];
                ushort4 h, l;
                h.x = f2bf(v.x); l.x = f2bf(v.x - bf2f(h.x));
                h.y = f2bf(v.y); l.y = f2bf(v.y - bf2f(h.y));
                h.z = f2bf(v.z); l.z = f2bf(v.z - bf2f(h.z));
                h.w = f2bf(v.w); l.w = f2bf(v.w - bf2f(h.w));
                const int off = (a_row + i * 64) * 32 + a_kc;
                *(ushort4*)(&Ah[nxt][off]) = h;
                *(ushort4*)(&Al[nxt][off]) = l;
            }
        }
        __syncthreads();
        cur = nxt;
    }

    // ---- in-register band attention ----
    const int c = lane & 15, rg = lane >> 4;
    const int hcol = col0 + wn * 64;            // head base col = h*64
    const float* kb = kf + (long)b * 256 * D_DIM + hcol + c;
    const float* vb = vf + (long)b * 256 * D_DIM + hcol + c;
#pragma unroll
    for (int mi = 0; mi < 8; ++mi) {
        float wgt[4][3];
        int   pos[4][3];
#pragma unroll
        for (int j = 0; j < 4; ++j) {
            const int tok = row0 + wm * 128 + mi * 16 + rg * 4 + j;
            const int idx = cidx[tok];
            float wsum = 0.f;
#pragma unroll
            for (int dp = 0; dp < 3; ++dp) {
                const int p = idx + dp - 1;
                const bool valid = (p >= 0) && (p < 256);
                const int pc = valid ? p : 0;
                const float* kr = kb + (long)pc * D_DIM;
                float dot = acc[mi][0][j] * kr[0]  + acc[mi][1][j] * kr[16]
                          + acc[mi][2][j] * kr[32] + acc[mi][3][j] * kr[48];
                dot += __shfl_xor(dot, 1);
                dot += __shfl_xor(dot, 2);
                dot += __shfl_xor(dot, 4);
                dot += __shfl_xor(dot, 8);
                const float s = dot * 0.125f;
                const float w = (valid && s > 0.f) ? s * s : 0.f;
                wsum += w; wgt[j][dp] = w; pos[j][dp] = pc;
            }
            const float inv = 1.0f / fmaxf(wsum, 1e-6f);
            wgt[j][0] *= inv; wgt[j][1] *= inv; wgt[j][2] *= inv;
        }
#pragma unroll
        for (int ni = 0; ni < 4; ++ni)
#pragma unroll
            for (int j = 0; j < 4; ++j) {
                float a = 0.f;
#pragma unroll
                for (int dp = 0; dp < 3; ++dp)
                    a += wgt[j][dp] * vb[(long)pos[j][dp] * D_DIM + ni * 16];
                acc[mi][ni][j] = a;
            }
    }

    // store ao (bf16)
#pragma unroll
    for (int mi = 0; mi < 8; ++mi)
#pragma unroll
        for (int ni = 0; ni < 4; ++ni)
#pragma unroll
            for (int j = 0; j < 4; ++j) {
                const long tok = row0 + wm * 128 + mi * 16 + rg * 4 + j;
                ao[tok * D_DIM + hcol + ni * 16 + c] = f2bf(acc[mi][ni][j]);
            }
}

// ---------------------------------------------------------------------------
// out = x + ao @ Wo^T, BM=256 x BN=256, bf16, double-buffered, f32 out.
// ---------------------------------------------------------------------------
__global__ __launch_bounds__(512, 2)
void gemm_out256(const unsigned short* __restrict__ A,
                 const unsigned short* __restrict__ W,
                 float* __restrict__ C, const float* __restrict__ resid)
{
    __shared__ unsigned short As[2][8192];
    __shared__ unsigned short Bs[2][8192];

    int bx, by;
    decode_grid(blockIdx.x, bx, by);
    const long row0 = (long)by * 256;
    const int  col0 = bx * 256;

    const int tid = threadIdx.x, lane = tid & 63, wave = tid >> 6;
    const int wm = wave >> 2, wn = wave & 3;
    const int fr = lane & 15, ks = lane >> 4;

    f32x4 acc[8][4] = {};

    const int s_row0 = tid >> 2,          s_k0 = (tid & 3) * 8;
    const int s_row1 = (tid >> 2) + 128;

    // prologue
    gload16(A + (row0 + s_row0) * D_DIM + s_k0, (char*)&As[0][0] + tid * 16);
    gload16(A + (row0 + s_row1) * D_DIM + s_k0, (char*)&As[0][0] + (tid + 512) * 16);
    gload16(W + (long)(col0 + s_row0) * D_DIM + s_k0, (char*)&Bs[0][0] + tid * 16);
    gload16(W + (long)(col0 + s_row1) * D_DIM + s_k0, (char*)&Bs[0][0] + (tid + 512) * 16);
    __syncthreads();

    int cur = 0;
    for (int t = 0; t < 32; ++t) {
        const int nxt = cur ^ 1;
        if (t < 31) {
            const int k0 = (t + 1) * 32;
            gload16(A + (row0 + s_row0) * D_DIM + k0 + s_k0, (char*)&As[nxt][0] + tid * 16);
            gload16(A + (row0 + s_row1) * D_DIM + k0 + s_k0, (char*)&As[nxt][0] + (tid + 512) * 16);
            gload16(W + (long)(col0 + s_row0) * D_DIM + k0 + s_k0, (char*)&Bs[nxt][0] + tid * 16);
            gload16(W + (long)(col0 + s_row1) * D_DIM + k0 + s_k0, (char*)&Bs[nxt][0] + (tid + 512) * 16);
        }

        short8 bfrag[4];
#pragma unroll
        for (int ni = 0; ni < 4; ++ni)
            bfrag[ni] = *(const short8*)(&Bs[cur][(wn * 64 + ni * 16 + fr) * 32 + ks * 8]);
#pragma unroll
        for (int mi = 0; mi < 8; ++mi) {
            const short8 a = *(const short8*)(&As[cur][(wm * 128 + mi * 16 + fr) * 32 + ks * 8]);
#pragma unroll
            for (int ni = 0; ni < 4; ++ni)
                acc[mi][ni] = __builtin_amdgcn_mfma_f32_16x16x32_bf16(a, bfrag[ni], acc[mi][ni], 0, 0, 0);
        }
        __syncthreads();
        cur = nxt;
    }

    const int c = lane & 15, rg = lane >> 4;
#pragma unroll
    for (int mi = 0; mi < 8; ++mi)
#pragma unroll
        for (int ni = 0; ni < 4; ++ni)
#pragma unroll
            for (int j = 0; j < 4; ++j) {
                const long row = row0 + wm * 128 + mi * 16 + rg * 4 + j;
                const int  col = col0 + wn * 64 + ni * 16 + c;
                C[row * D_DIM + col] = resid[row * D_DIM + col] + acc[mi][ni][j];
            }
}

// ---------------------------------------------------------------------------
extern "C" void kernel_launch(void* const* d_in, const int* in_sizes, int n_in,
                              void* d_out, int out_size, void* d_ws, size_t ws_size,
                              hipStream_t stream)
{
    const float* x    = (const float*)d_in[0];
    const float* ctx  = (const float*)d_in[1];
    const int*   cidx = (const int*)d_in[2];
    const float* gq   = (const float*)d_in[3];
    const float* gkv  = (const float*)d_in[4];
    const float* Wq   = (const float*)d_in[5];
    const float* Wk   = (const float*)d_in[6];
    const float* Wv   = (const float*)d_in[7];
    const float* Wo   = (const float*)d_in[8];
    float* out = (float*)d_out;

    char* ws = (char*)d_ws;
    const size_t MB = 1 << 20;
    unsigned short* wq_hi = (unsigned short*)(ws + 0 * MB);
    unsigned short* wq_lo = (unsigned short*)(ws + 2 * MB);
    unsigned short* wk_hi = (unsigned short*)(ws + 4 * MB);
    unsigned short* wk_lo = (unsigned short*)(ws + 6 * MB);
    unsigned short* wv_hi = (unsigned short*)(ws + 8 * MB);
    unsigned short* wv_lo = (unsigned short*)(ws + 10 * MB);
    unsigned short* wo_b  = (unsigned short*)(ws + 12 * MB);
    float* scale_x = (float*)(ws + 14 * MB);            // 64KB
    float* scale_c = (float*)(ws + 14 * MB + 131072);   // 4KB
    float* k_f = (float*)(ws + 15 * MB);                // 4MB
    float* v_f = (float*)(ws + 19 * MB);                // 4MB
    unsigned short* ao_b = (unsigned short*)(ws + 23 * MB);  // 32MB; total 55MB

    // 1. fold gamma into Wq/Wk/Wv, split hi/lo; Wo -> bf16
    convw_kernel<<<4096, 256, 0, stream>>>(Wq, Wk, Wv, Wo, gq, gkv, ws);
    // 2. rmsnorm row scales
    scales_kernel<<<16384, 256, 0, stream>>>(x, scale_x);
    scales_kernel<<<1024, 256, 0, stream>>>(ctx, scale_c);
    // 3. k,v (split precision, f32 out)
    gemm_split<<<dim3(8, 8, 2), 256, 0, stream>>>(ctx, wk_hi, wk_lo, wv_hi, wv_lo,
                                                  scale_c, k_f, v_f);
    // 4. fused q projection + band attention -> ao (bf16), 256x256 tiles
    qattn2_kernel<<<256, 512, 0, stream>>>(x, wq_hi, wq_lo, scale_x, k_f, v_f,
                                           cidx, ao_b);
    // 5. out = x + ao @ Wo^T, 256x256 tiles
    gemm_out256<<<256, 512, 0, stream>>>(ao_b, wo_b, out, x);
}